// Round 7
// baseline (224.923 us; speedup 1.0000x reference)
//
#include <hip/hip_runtime.h>
#include <hip/hip_bf16.h>
#include <cstdint>

// ---------- types ----------
typedef __attribute__((ext_vector_type(4))) float f32x4;
typedef __attribute__((ext_vector_type(16))) float f32x16;
typedef __attribute__((ext_vector_type(8))) __bf16 bf16x8;
typedef __attribute__((ext_vector_type(4))) unsigned u32x4;

#define SCALE_Q 0.08838834764831845f  /* 1/sqrt(128) */

__device__ __forceinline__ short bf16b(float f) {
  unsigned u = __builtin_bit_cast(unsigned, f);
  unsigned r = (u + 0x7fffu + ((u >> 16) & 1u)) >> 16;
  return (short)r;
}

__device__ __forceinline__ unsigned packbf(float lo, float hi) {
  return (unsigned)(unsigned short)bf16b(lo) |
         ((unsigned)(unsigned short)bf16b(hi) << 16);
}

__device__ __forceinline__ f32x4 mfma16(bf16x8 a, bf16x8 b, f32x4 c) {
  return __builtin_amdgcn_mfma_f32_16x16x32_bf16(a, b, c, 0, 0, 0);
}
__device__ __forceinline__ f32x16 mfma32(bf16x8 a, bf16x8 b, f32x16 c) {
  return __builtin_amdgcn_mfma_f32_32x32x16_bf16(a, b, c, 0, 0, 0);
}

__device__ __forceinline__ void async16(void* lds, const void* g) {
  __builtin_amdgcn_global_load_lds(
      (const __attribute__((address_space(1))) unsigned int*)g,
      (__attribute__((address_space(3))) unsigned int*)lds, 16, 0, 0);
}

// ---------- kernel 1: fp32 -> bf16 for queries/keys/values ----------
__global__ void cvt_x(const float* __restrict__ q, const float* __restrict__ k,
                      const float* __restrict__ v, short* __restrict__ out) {
  const float* src = (blockIdx.y == 0) ? q : (blockIdx.y == 1 ? k : v);
  short* dst = out + (size_t)blockIdx.y * 8388608;
  size_t i = (size_t)blockIdx.x * 256 + threadIdx.x;
  float4 f = reinterpret_cast<const float4*>(src)[i];
  short4 o;
  o.x = bf16b(f.x); o.y = bf16b(f.y); o.z = bf16b(f.z); o.w = bf16b(f.w);
  reinterpret_cast<short4*>(dst)[i] = o;
}

// ---------- kernel 2: transpose + convert weights -> WT[z][N][K] bf16 ----------
__global__ void cvt_w(const float* __restrict__ Wq, const float* __restrict__ Wk,
                      const float* __restrict__ Wv, const float* __restrict__ Wo,
                      short* __restrict__ out) {
  int z = blockIdx.z;
  const float* W = (z == 0) ? Wq : (z == 1) ? Wk : (z == 2) ? Wv : Wo;
  float scale = (z == 0) ? SCALE_Q : 1.0f;
  __shared__ float t[64][65];
  int n0 = blockIdx.x * 64, k0 = blockIdx.y * 64;
  int c = threadIdx.x & 63, r0 = threadIdx.x >> 6;
#pragma unroll
  for (int rr = 0; rr < 16; ++rr) {
    int r = rr * 4 + r0;
    t[r][c] = W[(size_t)(k0 + r) * 1024 + n0 + c];
  }
  __syncthreads();
  short* dst = out + (size_t)z * 1048576;
#pragma unroll
  for (int rr = 0; rr < 16; ++rr) {
    int r = rr * 4 + r0;
    dst[(size_t)(n0 + r) * 1024 + k0 + c] = bf16b(t[c][r] * scale);
  }
}

// ---------- kernel 3: 128x128 2-phase double-buffered GEMM ----------
// T3-minimum pipeline (§5.5): stage tile t+1 into the other LDS buffer FIRST,
// then ds_read+MFMA tile t, then one __syncthreads per tile (vmcnt0+lgkm0+bar).
// Staging latency overlaps the compute phase instead of the critical path.
// Keeps R6-proven: T2 both-sides swizzle (0 conflicts), T1 XCD chunk-swizzle,
// n-fastest tile order, fused out-proj (z=3), R2-proven epilogue layouts.
__global__ __launch_bounds__(256, 2) void gemm128(
    const short* __restrict__ Ab, const short* __restrict__ WT,
    const float* __restrict__ bq, const float* __restrict__ bk,
    const float* __restrict__ bv, const float* __restrict__ bo,
    short* __restrict__ Qg, short* __restrict__ Kg, short* __restrict__ Vtg,
    float* __restrict__ Out, int zbase, int nwg) {
  __shared__ short As[2][8192], Bs[2][8192];  // 64 KiB double buffer

  int cpx = nwg >> 3;
  int swz = ((int)blockIdx.x & 7) * cpx + ((int)blockIdx.x >> 3);
  int z, rem;
  if (zbase == 0) { z = swz >> 9; rem = swz & 511; }   // 512 tiles per z (64m x 8n)
  else { z = 3; rem = swz; }
  int m0 = (rem >> 3) * 128, n0 = (rem & 7) * 128;     // n fastest: A-panel reuse

  const short* A = (zbase == 0) ? Ab + (size_t)z * 8388608 : Ab;
  const short* Bn = WT + (size_t)z * 1048576;

  int tid = threadIdx.x;
  int lane = tid & 63, wave = tid >> 6;
  int wr = wave >> 1, wc = wave & 1, l15 = lane & 15, lg = lane >> 4;

  auto stage = [&](int t) {
    int buf = t & 1, k0 = t * 64;
#pragma unroll
    for (int i = 0; i < 4; ++i) {
      int r = (tid >> 3) + i * 32, c = tid & 7;
      int gc = c ^ (r & 7);  // inverse-swizzled source, linear LDS dest
      async16((char*)&As[buf][0] + i * 4096 + tid * 16,
              (const char*)A + ((size_t)(m0 + r) * 1024 + k0) * 2 + gc * 16);
      async16((char*)&Bs[buf][0] + i * 4096 + tid * 16,
              (const char*)Bn + ((size_t)(n0 + r) * 1024 + k0) * 2 + gc * 16);
    }
  };

  f32x4 acc[4][4];
#pragma unroll
  for (int mt = 0; mt < 4; ++mt)
#pragma unroll
    for (int nt = 0; nt < 4; ++nt) acc[mt][nt] = f32x4{0.f, 0.f, 0.f, 0.f};

  stage(0);
  __syncthreads();  // drains vmcnt(0): tile 0 resident

  for (int t = 0; t < 16; ++t) {
    if (t < 15) stage(t + 1);  // issue next-tile DMA first (other buffer)
    const char* Ac = (const char*)&As[t & 1][0];
    const char* Bc = (const char*)&Bs[t & 1][0];
#pragma unroll
    for (int kk = 0; kk < 2; ++kk) {
      bf16x8 a[4], b[4];
#pragma unroll
      for (int mt = 0; mt < 4; ++mt) {
        int r = wr * 64 + mt * 16 + l15;
        a[mt] = *(const bf16x8*)(Ac + r * 128 +
                                 ((lg * 16 + kk * 64) ^ ((r & 7) << 4)));
      }
#pragma unroll
      for (int nt = 0; nt < 4; ++nt) {
        int r = wc * 64 + nt * 16 + l15;
        b[nt] = *(const bf16x8*)(Bc + r * 128 +
                                 ((lg * 16 + kk * 64) ^ ((r & 7) << 4)));
      }
#pragma unroll
      for (int mt = 0; mt < 4; ++mt)
#pragma unroll
        for (int nt = 0; nt < 4; ++nt)
          acc[mt][nt] = mfma16(a[mt], b[nt], acc[mt][nt]);
    }
    __syncthreads();  // one vmcnt(0)+lgkm(0)+barrier per tile: next buf ready
  }

  // ---- epilogue (R2-proven layouts; z=3 fp32 direct) ----
#pragma unroll
  for (int mt = 0; mt < 4; ++mt)
#pragma unroll
    for (int nt = 0; nt < 4; ++nt) {
      int n = n0 + wc * 64 + nt * 16 + l15;
      float bb = (z == 0)   ? bq[n] * SCALE_Q
                 : (z == 1) ? bk[n]
                 : (z == 2) ? bv[n]
                            : bo[n];
#pragma unroll
      for (int j = 0; j < 4; ++j) {
        int m = m0 + wr * 64 + mt * 16 + lg * 4 + j;
        float cv = acc[mt][nt][j] + bb;
        if (z == 3) {
          Out[(size_t)m * 1024 + n] = cv;
        } else {
          short o = bf16b(cv);
          int s_ = m & 2047, b_ = m >> 11, h_ = n >> 7, e_ = n & 127;
          size_t bh = (size_t)b_ * 8 + h_;
          if (z == 0)
            Qg[(bh * 2048 + s_) * 128 + e_] = o;
          else if (z == 1)
            Kg[(bh * 2048 + s_) * 128 + (e_ ^ ((s_ & 15) << 3))] = o;
          else
            Vtg[(bh * 128 + e_) * 2048 + (s_ ^ (((e_ >> 1) & 7) << 3))] = o;
        }
      }
    }
}

// ---------- kernel 4: flash attention, 32x32 swapped-QK^T, in-register P ----------
__global__ __launch_bounds__(256, 2) void attn(const short* __restrict__ Qg,
                                               const short* __restrict__ Kg,
                                               const short* __restrict__ Vtg,
                                               short* __restrict__ Ctx) {
  __shared__ short Ks[2][8192];  // [64 s][128 e], e ^ ((s&15)<<3)
  __shared__ short Vs[2][8192];  // [64 r][(e&1)*64 + (s ^ ((r&7)<<3))], r=e>>1
  int tid = threadIdx.x;
  int lane = tid & 63, wave = tid >> 6;
  int l31 = lane & 31, h = lane >> 5;
  int bh = blockIdx.y, qb = blockIdx.x;
  int qbase = qb * 128 + wave * 32;
  const short* Qp = Qg + (size_t)bh * 2048 * 128;
  const char* Kbase = (const char*)(Kg + (size_t)bh * 2048 * 128);
  const char* Vbase = (const char*)(Vtg + (size_t)bh * 128 * 2048);

  auto stage = [&](int t, int buf) {
    int s0 = t * 64;
    char* kd = (char*)&Ks[buf][0];
    char* vd = (char*)&Vs[buf][0];
#pragma unroll
    for (int i = 0; i < 4; ++i)
      async16(kd + i * 4096 + tid * 16,
              Kbase + (size_t)s0 * 256 + i * 4096 + tid * 16);
#pragma unroll
    for (int i = 0; i < 4; ++i) {
      int e = i * 32 + 2 * (tid >> 4) + ((tid >> 3) & 1);
      async16(vd + i * 4096 + tid * 16,
              Vbase + (size_t)e * 4096 + s0 * 2 + (tid & 7) * 16);
    }
  };

  stage(0, 0);

  bf16x8 qa[8];
  const short* qrow = Qp + (size_t)(qbase + l31) * 128 + h * 8;
#pragma unroll
  for (int ksl = 0; ksl < 8; ++ksl) qa[ksl] = *(const bf16x8*)(qrow + ksl * 16);

  f32x16 acc[4];
#pragma unroll
  for (int i = 0; i < 4; ++i)
#pragma unroll
    for (int r = 0; r < 16; ++r) acc[i][r] = 0.f;
  float mrun = -1e30f, lrun = 0.f;

  int swK = (l31 & 15) << 3;
  int swV = ((l31 >> 1) & 7) << 3;

  for (int t = 0; t < 32; ++t) {
    int cur = t & 1;
    if (t < 31) {
      stage(t + 1, cur ^ 1);
      asm volatile("s_waitcnt vmcnt(8)" ::: "memory");
    } else {
      asm volatile("s_waitcnt vmcnt(0)" ::: "memory");
    }
    __builtin_amdgcn_s_barrier();

    const short* Kc = Ks[cur];
    const short* Vc = Vs[cur];

    f32x16 st0, st1;
#pragma unroll
    for (int r = 0; r < 16; ++r) { st0[r] = 0.f; st1[r] = 0.f; }
    __builtin_amdgcn_s_setprio(1);
#pragma unroll
    for (int ksl = 0; ksl < 8; ++ksl) {
      int col = (ksl * 16 + h * 8) ^ swK;
      bf16x8 ka0 = *(const bf16x8*)&Kc[l31 * 128 + col];
      bf16x8 ka1 = *(const bf16x8*)&Kc[(32 + l31) * 128 + col];
      st0 = mfma32(ka0, qa[ksl], st0);
      st1 = mfma32(ka1, qa[ksl], st1);
    }
    __builtin_amdgcn_s_setprio(0);

    float mx = st0[0];
#pragma unroll
    for (int r = 1; r < 16; ++r) mx = fmaxf(mx, st0[r]);
#pragma unroll
    for (int r = 0; r < 16; ++r) mx = fmaxf(mx, st1[r]);
    mx = fmaxf(mx, __shfl_xor(mx, 32));
    int skip = __all(mx - mrun <= 5.0f);
    float mn = mrun, sf = 1.f;
    if (!skip) {
      mn = fmaxf(mrun, mx);
      sf = __expf(mrun - mn);
      mrun = mn;
    }
    float rs = 0.f;
#pragma unroll
    for (int r = 0; r < 16; ++r) { float p = __expf(st0[r] - mn); st0[r] = p; rs += p; }
#pragma unroll
    for (int r = 0; r < 16; ++r) { float p = __expf(st1[r] - mn); st1[r] = p; rs += p; }
    rs += __shfl_xor(rs, 32);
    if (!skip) {
      lrun = lrun * sf + rs;
#pragma unroll
      for (int reg = 0; reg < 16; ++reg) {
        float s4 = __shfl(sf, (reg & 3) + 8 * (reg >> 2) + 4 * h);
#pragma unroll
        for (int nte = 0; nte < 4; ++nte) acc[nte][reg] *= s4;
      }
    } else {
      lrun += rs;
    }

    unsigned w0[8], w1[8];
#pragma unroll
    for (int m = 0; m < 8; ++m) {
      w0[m] = packbf(st0[2 * m], st0[2 * m + 1]);
      w1[m] = packbf(st1[2 * m], st1[2 * m + 1]);
    }
    bf16x8 pa[4];
#pragma unroll
    for (int ks = 0; ks < 4; ++ks) {
      const unsigned* w = (ks & 2) ? w1 : w0;
      int mb = (ks & 1) * 4;
      unsigned a0 = w[mb], b0 = w[mb + 2];
      unsigned a1 = w[mb + 1], b1 = w[mb + 3];
      asm volatile("v_permlane32_swap_b32 %0, %1" : "+v"(a0), "+v"(b0));
      asm volatile("v_permlane32_swap_b32 %0, %1" : "+v"(a1), "+v"(b1));
      u32x4 tt;
      tt[0] = a0; tt[1] = a1; tt[2] = b0; tt[3] = b1;
      pa[ks] = __builtin_bit_cast(bf16x8, tt);
    }

    __builtin_amdgcn_s_setprio(1);
#pragma unroll
    for (int nte = 0; nte < 4; ++nte) {
      int rbase = (nte * 16 + (l31 >> 1)) * 128 + (lane & 1) * 64;
#pragma unroll
      for (int ks = 0; ks < 4; ++ks) {
        int colk = (ks * 16 + h * 8) ^ swV;
        bf16x8 vb = *(const bf16x8*)&Vc[rbase + colk];
        acc[nte] = mfma32(pa[ks], vb, acc[nte]);
      }
    }
    __builtin_amdgcn_s_setprio(0);
    __builtin_amdgcn_s_barrier();
  }

  float inv = 1.0f / lrun;
  int b_ = bh >> 3, h_ = bh & 7;
#pragma unroll
  for (int reg = 0; reg < 16; ++reg) {
    int qr = (reg & 3) + 8 * (reg >> 2) + 4 * h;
    float iq = __shfl(inv, qr);
    int q = qbase + qr;
    short* orow = Ctx + (((size_t)b_ * 2048 + q) * 8 + h_) * 128;
#pragma unroll
    for (int nte = 0; nte < 4; ++nte)
      orow[nte * 32 + l31] = bf16b(acc[nte][reg] * iq);
  }
}

// ---------- host ----------
extern "C" void kernel_launch(void* const* d_in, const int* in_sizes, int n_in,
                              void* d_out, int out_size, void* d_ws, size_t ws_size,
                              hipStream_t stream) {
  const float* q = (const float*)d_in[0];
  const float* k = (const float*)d_in[1];
  const float* v = (const float*)d_in[2];
  const float* Wq = (const float*)d_in[3];
  const float* bq = (const float*)d_in[4];
  const float* Wk = (const float*)d_in[5];
  const float* bk = (const float*)d_in[6];
  const float* Wv = (const float*)d_in[7];
  const float* bv = (const float*)d_in[8];
  const float* Wo = (const float*)d_in[9];
  const float* bo = (const float*)d_in[10];
  float* out = (float*)d_out;

  short* ws = (short*)d_ws;
  short* X3 = ws;                               // 3 * 8388608 shorts
  short* WT = X3 + (size_t)3 * 8388608;         // 4 * 1048576 shorts
  short* Qg = WT + (size_t)4 * 1048576;
  short* Kg = Qg + (size_t)8388608;
  short* Vtg = Kg + (size_t)8388608;
  short* Ctx = X3;  // X dead after projections; reuse for attention output

  hipLaunchKernelGGL(cvt_x, dim3(8192, 3), dim3(256), 0, stream, q, k, v, X3);
  hipLaunchKernelGGL(cvt_w, dim3(16, 16, 4), dim3(256), 0, stream, Wq, Wk, Wv, Wo, WT);
  hipLaunchKernelGGL(gemm128, dim3(1536), dim3(256), 0, stream, X3, WT, bq, bk, bv,
                     bo, Qg, Kg, Vtg, out, 0, 1536);
  hipLaunchKernelGGL(attn, dim3(16, 32), dim3(256), 0, stream, Qg, Kg, Vtg, Ctx);
  hipLaunchKernelGGL(gemm128, dim3(512), dim3(256), 0, stream, Ctx, WT, bq, bk, bv,
                     bo, Qg, Kg, Vtg, out, 3, 512);
}

// Round 8
// 204.419 us; speedup vs baseline: 1.1003x; 1.1003x over previous
//
#include <hip/hip_runtime.h>
#include <hip/hip_bf16.h>
#include <cstdint>

// ---------- types ----------
typedef __attribute__((ext_vector_type(4))) float f32x4;
typedef __attribute__((ext_vector_type(16))) float f32x16;
typedef __attribute__((ext_vector_type(8))) __bf16 bf16x8;
typedef __attribute__((ext_vector_type(4))) unsigned u32x4;

#define SCALE_Q 0.08838834764831845f  /* 1/sqrt(128) */

__device__ __forceinline__ short bf16b(float f) {
  unsigned u = __builtin_bit_cast(unsigned, f);
  unsigned r = (u + 0x7fffu + ((u >> 16) & 1u)) >> 16;
  return (short)r;
}

__device__ __forceinline__ unsigned packbf(float lo, float hi) {
  return (unsigned)(unsigned short)bf16b(lo) |
         ((unsigned)(unsigned short)bf16b(hi) << 16);
}

__device__ __forceinline__ f32x4 mfma16(bf16x8 a, bf16x8 b, f32x4 c) {
  return __builtin_amdgcn_mfma_f32_16x16x32_bf16(a, b, c, 0, 0, 0);
}
__device__ __forceinline__ f32x16 mfma32(bf16x8 a, bf16x8 b, f32x16 c) {
  return __builtin_amdgcn_mfma_f32_32x32x16_bf16(a, b, c, 0, 0, 0);
}

__device__ __forceinline__ void async16(void* lds, const void* g) {
  __builtin_amdgcn_global_load_lds(
      (const __attribute__((address_space(1))) unsigned int*)g,
      (__attribute__((address_space(3))) unsigned int*)lds, 16, 0, 0);
}

// ---------- kernel 1: fp32 -> bf16 for queries/keys/values ----------
__global__ void cvt_x(const float* __restrict__ q, const float* __restrict__ k,
                      const float* __restrict__ v, short* __restrict__ out) {
  const float* src = (blockIdx.y == 0) ? q : (blockIdx.y == 1 ? k : v);
  short* dst = out + (size_t)blockIdx.y * 8388608;
  size_t i = (size_t)blockIdx.x * 256 + threadIdx.x;
  float4 f = reinterpret_cast<const float4*>(src)[i];
  short4 o;
  o.x = bf16b(f.x); o.y = bf16b(f.y); o.z = bf16b(f.z); o.w = bf16b(f.w);
  reinterpret_cast<short4*>(dst)[i] = o;
}

// ---------- kernel 2: transpose + convert weights -> WT[z][N][K] bf16 ----------
__global__ void cvt_w(const float* __restrict__ Wq, const float* __restrict__ Wk,
                      const float* __restrict__ Wv, const float* __restrict__ Wo,
                      short* __restrict__ out) {
  int z = blockIdx.z;
  const float* W = (z == 0) ? Wq : (z == 1) ? Wk : (z == 2) ? Wv : Wo;
  float scale = (z == 0) ? SCALE_Q : 1.0f;
  __shared__ float t[64][65];
  int n0 = blockIdx.x * 64, k0 = blockIdx.y * 64;
  int c = threadIdx.x & 63, r0 = threadIdx.x >> 6;
#pragma unroll
  for (int rr = 0; rr < 16; ++rr) {
    int r = rr * 4 + r0;
    t[r][c] = W[(size_t)(k0 + r) * 1024 + n0 + c];
  }
  __syncthreads();
  short* dst = out + (size_t)z * 1048576;
#pragma unroll
  for (int rr = 0; rr < 16; ++rr) {
    int r = rr * 4 + r0;
    dst[(size_t)(n0 + r) * 1024 + k0 + c] = bf16b(t[c][r] * scale);
  }
}

// ---------- kernel 3: 128x128 2-phase GEMM (R6-proven structure) ----------
// Changes vs R6: __launch_bounds__(256,4) (occupancy target 4+ blocks/CU);
// z=2 (Vt) epilogue via LDS transpose -> coalesced 16B stores (was 2B scatter
// with 4KB lane stride, 1.8x write amplification). Mainloop byte-identical.
__global__ __launch_bounds__(256, 4) void gemm128(
    const short* __restrict__ Ab, const short* __restrict__ WT,
    const float* __restrict__ bq, const float* __restrict__ bk,
    const float* __restrict__ bv, const float* __restrict__ bo,
    short* __restrict__ Qg, short* __restrict__ Kg, short* __restrict__ Vtg,
    float* __restrict__ Out, int zbase, int nwg) {
  __shared__ __align__(16) short LDSbuf[16384];  // 32 KiB: As | Bs, reused by epilogue
  short* As = LDSbuf;
  short* Bs = LDSbuf + 8192;

  int cpx = nwg >> 3;
  int swz = ((int)blockIdx.x & 7) * cpx + ((int)blockIdx.x >> 3);
  int z, rem;
  if (zbase == 0) { z = swz >> 9; rem = swz & 511; }   // 512 tiles per z (64m x 8n)
  else { z = 3; rem = swz; }
  int m0 = (rem >> 3) * 128, n0 = (rem & 7) * 128;     // n fastest: A-panel reuse

  const short* A = (zbase == 0) ? Ab + (size_t)z * 8388608 : Ab;
  const short* Bn = WT + (size_t)z * 1048576;

  int tid = threadIdx.x;
  int lane = tid & 63, wave = tid >> 6;
  int wr = wave >> 1, wc = wave & 1, l15 = lane & 15, lg = lane >> 4;

  f32x4 acc[4][4];
#pragma unroll
  for (int mt = 0; mt < 4; ++mt)
#pragma unroll
    for (int nt = 0; nt < 4; ++nt) acc[mt][nt] = f32x4{0.f, 0.f, 0.f, 0.f};

  for (int k0 = 0; k0 < 1024; k0 += 64) {
#pragma unroll
    for (int i = 0; i < 4; ++i) {
      int r = (tid >> 3) + i * 32, c = tid & 7;
      int gc = c ^ (r & 7);  // inverse-swizzled source, linear LDS dest
      async16((char*)As + i * 4096 + tid * 16,
              (const char*)A + ((size_t)(m0 + r) * 1024 + k0) * 2 + gc * 16);
      async16((char*)Bs + i * 4096 + tid * 16,
              (const char*)Bn + ((size_t)(n0 + r) * 1024 + k0) * 2 + gc * 16);
    }
    __syncthreads();
#pragma unroll
    for (int kk = 0; kk < 2; ++kk) {
      bf16x8 a[4], b[4];
#pragma unroll
      for (int mt = 0; mt < 4; ++mt) {
        int r = wr * 64 + mt * 16 + l15;
        a[mt] = *(const bf16x8*)((const char*)As + r * 128 +
                                 ((lg * 16 + kk * 64) ^ ((r & 7) << 4)));
      }
#pragma unroll
      for (int nt = 0; nt < 4; ++nt) {
        int r = wc * 64 + nt * 16 + l15;
        b[nt] = *(const bf16x8*)((const char*)Bs + r * 128 +
                                 ((lg * 16 + kk * 64) ^ ((r & 7) << 4)));
      }
#pragma unroll
      for (int mt = 0; mt < 4; ++mt)
#pragma unroll
        for (int nt = 0; nt < 4; ++nt)
          acc[mt][nt] = mfma16(a[mt], b[nt], acc[mt][nt]);
    }
    __syncthreads();
  }

  // ---- epilogue ----
  if (z == 2) {
    // Vt via LDS transpose: two passes (wc half each), coalesced 16B stores.
    unsigned* Lt = (unsigned*)LDSbuf;  // [64 e][68 words of s-pairs]
    int b_ = m0 >> 11, h_ = n0 >> 7;
    size_t bh = (size_t)b_ * 8 + h_;
    int sbase = m0 & 2047;
#pragma unroll
    for (int p = 0; p < 2; ++p) {
      if (wc == p) {
#pragma unroll
        for (int nt = 0; nt < 4; ++nt) {
          int el = nt * 16 + l15;  // row within this pass's 64 e-rows
          float bb = bv[n0 + p * 64 + el];
#pragma unroll
          for (int mt = 0; mt < 4; ++mt) {
            int sw = wr * 32 + mt * 8 + lg * 2;  // word index (s>>1), even
            unsigned lo = packbf(acc[mt][nt][0] + bb, acc[mt][nt][1] + bb);
            unsigned hi = packbf(acc[mt][nt][2] + bb, acc[mt][nt][3] + bb);
            *(uint2*)&Lt[el * 68 + sw] = make_uint2(lo, hi);  // b64, 8B aligned
          }
        }
      }
      asm volatile("s_waitcnt lgkmcnt(0)" ::: "memory");
      __builtin_amdgcn_s_barrier();
      {
        int row = tid >> 2, ch = tid & 3;
        int e_ = p * 64 + row;  // n0 multiple of 128 -> e = n-local
        int sx = ((e_ >> 1) & 7) << 3;
#pragma unroll
        for (int i = 0; i < 4; ++i) {
          int w = ch * 16 + i * 4;               // 4-word aligned -> b128 ok
          u32x4 val = *(const u32x4*)&Lt[row * 68 + w];
          int sb = (sbase + w * 2) ^ sx;         // 8-short granule, 16B aligned
          *(u32x4*)&Vtg[(bh * 128 + e_) * 2048 + sb] = val;
        }
      }
      asm volatile("s_waitcnt lgkmcnt(0)" ::: "memory");
      __builtin_amdgcn_s_barrier();
    }
  } else {
#pragma unroll
    for (int mt = 0; mt < 4; ++mt)
#pragma unroll
      for (int nt = 0; nt < 4; ++nt) {
        int n = n0 + wc * 64 + nt * 16 + l15;
        float bb = (z == 0)   ? bq[n] * SCALE_Q
                   : (z == 1) ? bk[n]
                              : bo[n];
#pragma unroll
        for (int j = 0; j < 4; ++j) {
          int m = m0 + wr * 64 + mt * 16 + lg * 4 + j;
          float cv = acc[mt][nt][j] + bb;
          if (z == 3) {
            Out[(size_t)m * 1024 + n] = cv;
          } else {
            short o = bf16b(cv);
            int s_ = m & 2047, b_ = m >> 11, h_ = n >> 7, e_ = n & 127;
            size_t bh = (size_t)b_ * 8 + h_;
            if (z == 0)
              Qg[(bh * 2048 + s_) * 128 + e_] = o;
            else
              Kg[(bh * 2048 + s_) * 128 + (e_ ^ ((s_ & 15) << 3))] = o;
          }
        }
      }
  }
}

// ---------- kernel 4: flash attention, 32x32 swapped-QK^T, in-register P ----------
__global__ __launch_bounds__(256, 2) void attn(const short* __restrict__ Qg,
                                               const short* __restrict__ Kg,
                                               const short* __restrict__ Vtg,
                                               short* __restrict__ Ctx) {
  __shared__ short Ks[2][8192];  // [64 s][128 e], e ^ ((s&15)<<3)
  __shared__ short Vs[2][8192];  // [64 r][(e&1)*64 + (s ^ ((r&7)<<3))], r=e>>1
  int tid = threadIdx.x;
  int lane = tid & 63, wave = tid >> 6;
  int l31 = lane & 31, h = lane >> 5;
  int bh = blockIdx.y, qb = blockIdx.x;
  int qbase = qb * 128 + wave * 32;
  const short* Qp = Qg + (size_t)bh * 2048 * 128;
  const char* Kbase = (const char*)(Kg + (size_t)bh * 2048 * 128);
  const char* Vbase = (const char*)(Vtg + (size_t)bh * 128 * 2048);

  auto stage = [&](int t, int buf) {
    int s0 = t * 64;
    char* kd = (char*)&Ks[buf][0];
    char* vd = (char*)&Vs[buf][0];
#pragma unroll
    for (int i = 0; i < 4; ++i)
      async16(kd + i * 4096 + tid * 16,
              Kbase + (size_t)s0 * 256 + i * 4096 + tid * 16);
#pragma unroll
    for (int i = 0; i < 4; ++i) {
      int e = i * 32 + 2 * (tid >> 4) + ((tid >> 3) & 1);
      async16(vd + i * 4096 + tid * 16,
              Vbase + (size_t)e * 4096 + s0 * 2 + (tid & 7) * 16);
    }
  };

  stage(0, 0);

  bf16x8 qa[8];
  const short* qrow = Qp + (size_t)(qbase + l31) * 128 + h * 8;
#pragma unroll
  for (int ksl = 0; ksl < 8; ++ksl) qa[ksl] = *(const bf16x8*)(qrow + ksl * 16);

  f32x16 acc[4];
#pragma unroll
  for (int i = 0; i < 4; ++i)
#pragma unroll
    for (int r = 0; r < 16; ++r) acc[i][r] = 0.f;
  float mrun = -1e30f, lrun = 0.f;

  int swK = (l31 & 15) << 3;
  int swV = ((l31 >> 1) & 7) << 3;

  for (int t = 0; t < 32; ++t) {
    int cur = t & 1;
    if (t < 31) {
      stage(t + 1, cur ^ 1);
      asm volatile("s_waitcnt vmcnt(8)" ::: "memory");
    } else {
      asm volatile("s_waitcnt vmcnt(0)" ::: "memory");
    }
    __builtin_amdgcn_s_barrier();

    const short* Kc = Ks[cur];
    const short* Vc = Vs[cur];

    f32x16 st0, st1;
#pragma unroll
    for (int r = 0; r < 16; ++r) { st0[r] = 0.f; st1[r] = 0.f; }
    __builtin_amdgcn_s_setprio(1);
#pragma unroll
    for (int ksl = 0; ksl < 8; ++ksl) {
      int col = (ksl * 16 + h * 8) ^ swK;
      bf16x8 ka0 = *(const bf16x8*)&Kc[l31 * 128 + col];
      bf16x8 ka1 = *(const bf16x8*)&Kc[(32 + l31) * 128 + col];
      st0 = mfma32(ka0, qa[ksl], st0);
      st1 = mfma32(ka1, qa[ksl], st1);
    }
    __builtin_amdgcn_s_setprio(0);

    float mx = st0[0];
#pragma unroll
    for (int r = 1; r < 16; ++r) mx = fmaxf(mx, st0[r]);
#pragma unroll
    for (int r = 0; r < 16; ++r) mx = fmaxf(mx, st1[r]);
    mx = fmaxf(mx, __shfl_xor(mx, 32));
    int skip = __all(mx - mrun <= 5.0f);
    float mn = mrun, sf = 1.f;
    if (!skip) {
      mn = fmaxf(mrun, mx);
      sf = __expf(mrun - mn);
      mrun = mn;
    }
    float rs = 0.f;
#pragma unroll
    for (int r = 0; r < 16; ++r) { float p = __expf(st0[r] - mn); st0[r] = p; rs += p; }
#pragma unroll
    for (int r = 0; r < 16; ++r) { float p = __expf(st1[r] - mn); st1[r] = p; rs += p; }
    rs += __shfl_xor(rs, 32);
    if (!skip) {
      lrun = lrun * sf + rs;
#pragma unroll
      for (int reg = 0; reg < 16; ++reg) {
        float s4 = __shfl(sf, (reg & 3) + 8 * (reg >> 2) + 4 * h);
#pragma unroll
        for (int nte = 0; nte < 4; ++nte) acc[nte][reg] *= s4;
      }
    } else {
      lrun += rs;
    }

    unsigned w0[8], w1[8];
#pragma unroll
    for (int m = 0; m < 8; ++m) {
      w0[m] = packbf(st0[2 * m], st0[2 * m + 1]);
      w1[m] = packbf(st1[2 * m], st1[2 * m + 1]);
    }
    bf16x8 pa[4];
#pragma unroll
    for (int ks = 0; ks < 4; ++ks) {
      const unsigned* w = (ks & 2) ? w1 : w0;
      int mb = (ks & 1) * 4;
      unsigned a0 = w[mb], b0 = w[mb + 2];
      unsigned a1 = w[mb + 1], b1 = w[mb + 3];
      asm volatile("v_permlane32_swap_b32 %0, %1" : "+v"(a0), "+v"(b0));
      asm volatile("v_permlane32_swap_b32 %0, %1" : "+v"(a1), "+v"(b1));
      u32x4 tt;
      tt[0] = a0; tt[1] = a1; tt[2] = b0; tt[3] = b1;
      pa[ks] = __builtin_bit_cast(bf16x8, tt);
    }

    __builtin_amdgcn_s_setprio(1);
#pragma unroll
    for (int nte = 0; nte < 4; ++nte) {
      int rbase = (nte * 16 + (l31 >> 1)) * 128 + (lane & 1) * 64;
#pragma unroll
      for (int ks = 0; ks < 4; ++ks) {
        int colk = (ks * 16 + h * 8) ^ swV;
        bf16x8 vb = *(const bf16x8*)&Vc[rbase + colk];
        acc[nte] = mfma32(pa[ks], vb, acc[nte]);
      }
    }
    __builtin_amdgcn_s_setprio(0);
    __builtin_amdgcn_s_barrier();
  }

  float inv = 1.0f / lrun;
  int b_ = bh >> 3, h_ = bh & 7;
#pragma unroll
  for (int reg = 0; reg < 16; ++reg) {
    int qr = (reg & 3) + 8 * (reg >> 2) + 4 * h;
    float iq = __shfl(inv, qr);
    int q = qbase + qr;
    short* orow = Ctx + (((size_t)b_ * 2048 + q) * 8 + h_) * 128;
#pragma unroll
    for (int nte = 0; nte < 4; ++nte)
      orow[nte * 32 + l31] = bf16b(acc[nte][reg] * iq);
  }
}

// ---------- host ----------
extern "C" void kernel_launch(void* const* d_in, const int* in_sizes, int n_in,
                              void* d_out, int out_size, void* d_ws, size_t ws_size,
                              hipStream_t stream) {
  const float* q = (const float*)d_in[0];
  const float* k = (const float*)d_in[1];
  const float* v = (const float*)d_in[2];
  const float* Wq = (const float*)d_in[3];
  const float* bq = (const float*)d_in[4];
  const float* Wk = (const float*)d_in[5];
  const float* bk = (const float*)d_in[6];
  const float* Wv = (const float*)d_in[7];
  const float* bv = (const float*)d_in[8];
  const float* Wo = (const float*)d_in[9];
  const float* bo = (const float*)d_in[10];
  float* out = (float*)d_out;

  short* ws = (short*)d_ws;
  short* X3 = ws;                               // 3 * 8388608 shorts
  short* WT = X3 + (size_t)3 * 8388608;         // 4 * 1048576 shorts
  short* Qg = WT + (size_t)4 * 1048576;
  short* Kg = Qg + (size_t)8388608;
  short* Vtg = Kg + (size_t)8388608;
  short* Ctx = X3;  // X dead after projections; reuse for attention output

  hipLaunchKernelGGL(cvt_x, dim3(8192, 3), dim3(256), 0, stream, q, k, v, X3);
  hipLaunchKernelGGL(cvt_w, dim3(16, 16, 4), dim3(256), 0, stream, Wq, Wk, Wv, Wo, WT);
  hipLaunchKernelGGL(gemm128, dim3(1536), dim3(256), 0, stream, X3, WT, bq, bk, bv,
                     bo, Qg, Kg, Vtg, out, 0, 1536);
  hipLaunchKernelGGL(attn, dim3(16, 32), dim3(256), 0, stream, Qg, Kg, Vtg, Ctx);
  hipLaunchKernelGGL(gemm128, dim3(512), dim3(256), 0, stream, Ctx, WT, bq, bk, bv,
                     bo, Qg, Kg, Vtg, out, 3, 512);
}

// Round 9
// 189.481 us; speedup vs baseline: 1.1870x; 1.0788x over previous
//
#include <hip/hip_runtime.h>
#include <hip/hip_bf16.h>
#include <cstdint>

// ---------- types ----------
typedef __attribute__((ext_vector_type(4))) float f32x4;
typedef __attribute__((ext_vector_type(16))) float f32x16;
typedef __attribute__((ext_vector_type(8))) __bf16 bf16x8;
typedef __attribute__((ext_vector_type(4))) unsigned u32x4;

// 1/sqrt(128) * log2(e): softmax runs in exp2 domain (v_exp_f32 IS 2^x)
#define SCALE_Q 0.12751744f

__device__ __forceinline__ short bf16b(float f) {
  unsigned u = __builtin_bit_cast(unsigned, f);
  unsigned r = (u + 0x7fffu + ((u >> 16) & 1u)) >> 16;
  return (short)r;
}

// hardware packed f32x2 -> bf16x2 (RNE), one instruction
__device__ __forceinline__ unsigned packbf(float lo, float hi) {
  unsigned r;
  asm("v_cvt_pk_bf16_f32 %0, %1, %2" : "=v"(r) : "v"(lo), "v"(hi));
  return r;
}

__device__ __forceinline__ float exp2fast(float x) {
  float r;
  asm("v_exp_f32 %0, %1" : "=v"(r) : "v"(x));
  return r;
}

__device__ __forceinline__ f32x4 mfma16(bf16x8 a, bf16x8 b, f32x4 c) {
  return __builtin_amdgcn_mfma_f32_16x16x32_bf16(a, b, c, 0, 0, 0);
}
__device__ __forceinline__ f32x16 mfma32(bf16x8 a, bf16x8 b, f32x16 c) {
  return __builtin_amdgcn_mfma_f32_32x32x16_bf16(a, b, c, 0, 0, 0);
}

__device__ __forceinline__ void async16(void* lds, const void* g) {
  __builtin_amdgcn_global_load_lds(
      (const __attribute__((address_space(1))) unsigned int*)g,
      (__attribute__((address_space(3))) unsigned int*)lds, 16, 0, 0);
}

// ---------- kernel 1: fp32 -> bf16 for queries/keys/values ----------
__global__ void cvt_x(const float* __restrict__ q, const float* __restrict__ k,
                      const float* __restrict__ v, short* __restrict__ out) {
  const float* src = (blockIdx.y == 0) ? q : (blockIdx.y == 1 ? k : v);
  short* dst = out + (size_t)blockIdx.y * 8388608;
  size_t i = (size_t)blockIdx.x * 256 + threadIdx.x;
  float4 f = reinterpret_cast<const float4*>(src)[i];
  short4 o;
  o.x = bf16b(f.x); o.y = bf16b(f.y); o.z = bf16b(f.z); o.w = bf16b(f.w);
  reinterpret_cast<short4*>(dst)[i] = o;
}

// ---------- kernel 2: transpose + convert weights -> WT[z][N][K] bf16 ----------
__global__ void cvt_w(const float* __restrict__ Wq, const float* __restrict__ Wk,
                      const float* __restrict__ Wv, const float* __restrict__ Wo,
                      short* __restrict__ out) {
  int z = blockIdx.z;
  const float* W = (z == 0) ? Wq : (z == 1) ? Wk : (z == 2) ? Wv : Wo;
  float scale = (z == 0) ? SCALE_Q : 1.0f;
  __shared__ float t[64][65];
  int n0 = blockIdx.x * 64, k0 = blockIdx.y * 64;
  int c = threadIdx.x & 63, r0 = threadIdx.x >> 6;
#pragma unroll
  for (int rr = 0; rr < 16; ++rr) {
    int r = rr * 4 + r0;
    t[r][c] = W[(size_t)(k0 + r) * 1024 + n0 + c];
  }
  __syncthreads();
  short* dst = out + (size_t)z * 1048576;
#pragma unroll
  for (int rr = 0; rr < 16; ++rr) {
    int r = rr * 4 + r0;
    dst[(size_t)(n0 + r) * 1024 + k0 + c] = bf16b(t[c][r] * scale);
  }
}

// ---------- kernel 3: 128x128 2-phase GEMM (R6/R8-proven structure) ----------
__global__ __launch_bounds__(256, 4) void gemm128(
    const short* __restrict__ Ab, const short* __restrict__ WT,
    const float* __restrict__ bq, const float* __restrict__ bk,
    const float* __restrict__ bv, const float* __restrict__ bo,
    short* __restrict__ Qg, short* __restrict__ Kg, short* __restrict__ Vtg,
    float* __restrict__ Out, int zbase, int nwg) {
  __shared__ __align__(16) short LDSbuf[16384];  // 32 KiB: As | Bs, reused by epilogue
  short* As = LDSbuf;
  short* Bs = LDSbuf + 8192;

  int cpx = nwg >> 3;
  int swz = ((int)blockIdx.x & 7) * cpx + ((int)blockIdx.x >> 3);
  int z, rem;
  if (zbase == 0) { z = swz >> 9; rem = swz & 511; }   // 512 tiles per z (64m x 8n)
  else { z = 3; rem = swz; }
  int m0 = (rem >> 3) * 128, n0 = (rem & 7) * 128;     // n fastest: A-panel reuse

  const short* A = (zbase == 0) ? Ab + (size_t)z * 8388608 : Ab;
  const short* Bn = WT + (size_t)z * 1048576;

  int tid = threadIdx.x;
  int lane = tid & 63, wave = tid >> 6;
  int wr = wave >> 1, wc = wave & 1, l15 = lane & 15, lg = lane >> 4;

  f32x4 acc[4][4];
#pragma unroll
  for (int mt = 0; mt < 4; ++mt)
#pragma unroll
    for (int nt = 0; nt < 4; ++nt) acc[mt][nt] = f32x4{0.f, 0.f, 0.f, 0.f};

  for (int k0 = 0; k0 < 1024; k0 += 64) {
#pragma unroll
    for (int i = 0; i < 4; ++i) {
      int r = (tid >> 3) + i * 32, c = tid & 7;
      int gc = c ^ (r & 7);  // inverse-swizzled source, linear LDS dest
      async16((char*)As + i * 4096 + tid * 16,
              (const char*)A + ((size_t)(m0 + r) * 1024 + k0) * 2 + gc * 16);
      async16((char*)Bs + i * 4096 + tid * 16,
              (const char*)Bn + ((size_t)(n0 + r) * 1024 + k0) * 2 + gc * 16);
    }
    __syncthreads();
#pragma unroll
    for (int kk = 0; kk < 2; ++kk) {
      bf16x8 a[4], b[4];
#pragma unroll
      for (int mt = 0; mt < 4; ++mt) {
        int r = wr * 64 + mt * 16 + l15;
        a[mt] = *(const bf16x8*)((const char*)As + r * 128 +
                                 ((lg * 16 + kk * 64) ^ ((r & 7) << 4)));
      }
#pragma unroll
      for (int nt = 0; nt < 4; ++nt) {
        int r = wc * 64 + nt * 16 + l15;
        b[nt] = *(const bf16x8*)((const char*)Bs + r * 128 +
                                 ((lg * 16 + kk * 64) ^ ((r & 7) << 4)));
      }
#pragma unroll
      for (int mt = 0; mt < 4; ++mt)
#pragma unroll
        for (int nt = 0; nt < 4; ++nt)
          acc[mt][nt] = mfma16(a[mt], b[nt], acc[mt][nt]);
    }
    __syncthreads();
  }

  // ---- epilogue ----
  if (z == 2) {
    // Vt via LDS transpose: two passes (wc half each), coalesced 16B stores.
    unsigned* Lt = (unsigned*)LDSbuf;  // [64 e][68 words of s-pairs]
    int b_ = m0 >> 11, h_ = n0 >> 7;
    size_t bh = (size_t)b_ * 8 + h_;
    int sbase = m0 & 2047;
#pragma unroll
    for (int p = 0; p < 2; ++p) {
      if (wc == p) {
#pragma unroll
        for (int nt = 0; nt < 4; ++nt) {
          int el = nt * 16 + l15;  // row within this pass's 64 e-rows
          float bb = bv[n0 + p * 64 + el];
#pragma unroll
          for (int mt = 0; mt < 4; ++mt) {
            int sw = wr * 32 + mt * 8 + lg * 2;  // word index (s>>1), even
            unsigned lo = packbf(acc[mt][nt][0] + bb, acc[mt][nt][1] + bb);
            unsigned hi = packbf(acc[mt][nt][2] + bb, acc[mt][nt][3] + bb);
            *(uint2*)&Lt[el * 68 + sw] = make_uint2(lo, hi);  // b64, 8B aligned
          }
        }
      }
      asm volatile("s_waitcnt lgkmcnt(0)" ::: "memory");
      __builtin_amdgcn_s_barrier();
      {
        int row = tid >> 2, ch = tid & 3;
        int e_ = p * 64 + row;  // n0 multiple of 128 -> e = n-local
        int sx = ((e_ >> 1) & 7) << 3;
#pragma unroll
        for (int i = 0; i < 4; ++i) {
          int w = ch * 16 + i * 4;               // 4-word aligned -> b128 ok
          u32x4 val = *(const u32x4*)&Lt[row * 68 + w];
          int sb = (sbase + w * 2) ^ sx;         // 8-short granule, 16B aligned
          *(u32x4*)&Vtg[(bh * 128 + e_) * 2048 + sb] = val;
        }
      }
      asm volatile("s_waitcnt lgkmcnt(0)" ::: "memory");
      __builtin_amdgcn_s_barrier();
    }
  } else {
#pragma unroll
    for (int mt = 0; mt < 4; ++mt)
#pragma unroll
      for (int nt = 0; nt < 4; ++nt) {
        int n = n0 + wc * 64 + nt * 16 + l15;
        float bb = (z == 0)   ? bq[n] * SCALE_Q
                   : (z == 1) ? bk[n]
                              : bo[n];
#pragma unroll
        for (int j = 0; j < 4; ++j) {
          int m = m0 + wr * 64 + mt * 16 + lg * 4 + j;
          float cv = acc[mt][nt][j] + bb;
          if (z == 3) {
            Out[(size_t)m * 1024 + n] = cv;
          } else {
            short o = bf16b(cv);
            int s_ = m & 2047, b_ = m >> 11, h_ = n >> 7, e_ = n & 127;
            size_t bh = (size_t)b_ * 8 + h_;
            if (z == 0)
              Qg[(bh * 2048 + s_) * 128 + e_] = o;
            else
              Kg[(bh * 2048 + s_) * 128 + (e_ ^ ((s_ & 15) << 3))] = o;
          }
        }
      }
  }
}

// ---------- kernel 4: flash attention, 32x32 swapped-QK^T, in-register P ----------
// exp2-domain softmax (log2e folded into Q scale); hw cvt_pk P-pack;
// XCD chunk-swizzle: each XCD owns 4 heads -> K/V working set = its 4MB L2.
__global__ __launch_bounds__(256, 2) void attn(const short* __restrict__ Qg,
                                               const short* __restrict__ Kg,
                                               const short* __restrict__ Vtg,
                                               short* __restrict__ Ctx) {
  __shared__ short Ks[2][8192];  // [64 s][128 e], e ^ ((s&15)<<3)
  __shared__ short Vs[2][8192];  // [64 r][(e&1)*64 + (s ^ ((r&7)<<3))], r=e>>1
  int tid = threadIdx.x;
  int lane = tid & 63, wave = tid >> 6;
  int l31 = lane & 31, h = lane >> 5;
  int bid = blockIdx.x;
  int swz = (bid & 7) * 64 + (bid >> 3);  // XCD j -> bh in {4j..4j+3}
  int bh = swz >> 4, qb = swz & 15;
  int qbase = qb * 128 + wave * 32;
  const short* Qp = Qg + (size_t)bh * 2048 * 128;
  const char* Kbase = (const char*)(Kg + (size_t)bh * 2048 * 128);
  const char* Vbase = (const char*)(Vtg + (size_t)bh * 128 * 2048);

  auto stage = [&](int t, int buf) {
    int s0 = t * 64;
    char* kd = (char*)&Ks[buf][0];
    char* vd = (char*)&Vs[buf][0];
#pragma unroll
    for (int i = 0; i < 4; ++i)
      async16(kd + i * 4096 + tid * 16,
              Kbase + (size_t)s0 * 256 + i * 4096 + tid * 16);
#pragma unroll
    for (int i = 0; i < 4; ++i) {
      int e = i * 32 + 2 * (tid >> 4) + ((tid >> 3) & 1);
      async16(vd + i * 4096 + tid * 16,
              Vbase + (size_t)e * 4096 + s0 * 2 + (tid & 7) * 16);
    }
  };

  stage(0, 0);

  bf16x8 qa[8];
  const short* qrow = Qp + (size_t)(qbase + l31) * 128 + h * 8;
#pragma unroll
  for (int ksl = 0; ksl < 8; ++ksl) qa[ksl] = *(const bf16x8*)(qrow + ksl * 16);

  f32x16 acc[4];
#pragma unroll
  for (int i = 0; i < 4; ++i)
#pragma unroll
    for (int r = 0; r < 16; ++r) acc[i][r] = 0.f;
  float mrun = -1e30f, lrun = 0.f;

  int swK = (l31 & 15) << 3;
  int swV = ((l31 >> 1) & 7) << 3;

  for (int t = 0; t < 32; ++t) {
    int cur = t & 1;
    if (t < 31) {
      stage(t + 1, cur ^ 1);
      asm volatile("s_waitcnt vmcnt(8)" ::: "memory");
    } else {
      asm volatile("s_waitcnt vmcnt(0)" ::: "memory");
    }
    __builtin_amdgcn_s_barrier();

    const short* Kc = Ks[cur];
    const short* Vc = Vs[cur];

    f32x16 st0, st1;
#pragma unroll
    for (int r = 0; r < 16; ++r) { st0[r] = 0.f; st1[r] = 0.f; }
    __builtin_amdgcn_s_setprio(1);
#pragma unroll
    for (int ksl = 0; ksl < 8; ++ksl) {
      int col = (ksl * 16 + h * 8) ^ swK;
      bf16x8 ka0 = *(const bf16x8*)&Kc[l31 * 128 + col];
      bf16x8 ka1 = *(const bf16x8*)&Kc[(32 + l31) * 128 + col];
      st0 = mfma32(ka0, qa[ksl], st0);
      st1 = mfma32(ka1, qa[ksl], st1);
    }
    __builtin_amdgcn_s_setprio(0);

    float mx = st0[0];
#pragma unroll
    for (int r = 1; r < 16; ++r) mx = fmaxf(mx, st0[r]);
#pragma unroll
    for (int r = 0; r < 16; ++r) mx = fmaxf(mx, st1[r]);
    mx = fmaxf(mx, __shfl_xor(mx, 32));
    int skip = __all(mx - mrun <= 7.0f);  // log2 units: P bounded by 2^7
    float mn = mrun, sf = 1.f;
    if (!skip) {
      mn = fmaxf(mrun, mx);
      sf = exp2fast(mrun - mn);
      mrun = mn;
    }
    float rs = 0.f;
#pragma unroll
    for (int r = 0; r < 16; ++r) { float p = exp2fast(st0[r] - mn); st0[r] = p; rs += p; }
#pragma unroll
    for (int r = 0; r < 16; ++r) { float p = exp2fast(st1[r] - mn); st1[r] = p; rs += p; }
    rs += __shfl_xor(rs, 32);
    if (!skip) {
      lrun = lrun * sf + rs;
#pragma unroll
      for (int reg = 0; reg < 16; ++reg) {
        float s4 = __shfl(sf, (reg & 3) + 8 * (reg >> 2) + 4 * h);
#pragma unroll
        for (int nte = 0; nte < 4; ++nte) acc[nte][reg] *= s4;
      }
    } else {
      lrun += rs;
    }

    unsigned w0[8], w1[8];
#pragma unroll
    for (int m = 0; m < 8; ++m) {
      w0[m] = packbf(st0[2 * m], st0[2 * m + 1]);
      w1[m] = packbf(st1[2 * m], st1[2 * m + 1]);
    }
    bf16x8 pa[4];
#pragma unroll
    for (int ks = 0; ks < 4; ++ks) {
      const unsigned* w = (ks & 2) ? w1 : w0;
      int mb = (ks & 1) * 4;
      unsigned a0 = w[mb], b0 = w[mb + 2];
      unsigned a1 = w[mb + 1], b1 = w[mb + 3];
      asm volatile("v_permlane32_swap_b32 %0, %1" : "+v"(a0), "+v"(b0));
      asm volatile("v_permlane32_swap_b32 %0, %1" : "+v"(a1), "+v"(b1));
      u32x4 tt;
      tt[0] = a0; tt[1] = a1; tt[2] = b0; tt[3] = b1;
      pa[ks] = __builtin_bit_cast(bf16x8, tt);
    }

    __builtin_amdgcn_s_setprio(1);
#pragma unroll
    for (int nte = 0; nte < 4; ++nte) {
      int rbase = (nte * 16 + (l31 >> 1)) * 128 + (lane & 1) * 64;
#pragma unroll
      for (int ks = 0; ks < 4; ++ks) {
        int colk = (ks * 16 + h * 8) ^ swV;
        bf16x8 vb = *(const bf16x8*)&Vc[rbase + colk];
        acc[nte] = mfma32(pa[ks], vb, acc[nte]);
      }
    }
    __builtin_amdgcn_s_setprio(0);
    __builtin_amdgcn_s_barrier();
  }

  float inv = 1.0f / lrun;
  int b_ = bh >> 3, h_ = bh & 7;
#pragma unroll
  for (int reg = 0; reg < 16; ++reg) {
    int qr = (reg & 3) + 8 * (reg >> 2) + 4 * h;
    float iq = __shfl(inv, qr);
    int q = qbase + qr;
    short* orow = Ctx + (((size_t)b_ * 2048 + q) * 8 + h_) * 128;
#pragma unroll
    for (int nte = 0; nte < 4; ++nte)
      orow[nte * 32 + l31] = bf16b(acc[nte][reg] * iq);
  }
}

// ---------- host ----------
extern "C" void kernel_launch(void* const* d_in, const int* in_sizes, int n_in,
                              void* d_out, int out_size, void* d_ws, size_t ws_size,
                              hipStream_t stream) {
  const float* q = (const float*)d_in[0];
  const float* k = (const float*)d_in[1];
  const float* v = (const float*)d_in[2];
  const float* Wq = (const float*)d_in[3];
  const float* bq = (const float*)d_in[4];
  const float* Wk = (const float*)d_in[5];
  const float* bk = (const float*)d_in[6];
  const float* Wv = (const float*)d_in[7];
  const float* bv = (const float*)d_in[8];
  const float* Wo = (const float*)d_in[9];
  const float* bo = (const float*)d_in[10];
  float* out = (float*)d_out;

  short* ws = (short*)d_ws;
  short* X3 = ws;                               // 3 * 8388608 shorts
  short* WT = X3 + (size_t)3 * 8388608;         // 4 * 1048576 shorts
  short* Qg = WT + (size_t)4 * 1048576;
  short* Kg = Qg + (size_t)8388608;
  short* Vtg = Kg + (size_t)8388608;
  short* Ctx = X3;  // X dead after projections; reuse for attention output

  hipLaunchKernelGGL(cvt_x, dim3(8192, 3), dim3(256), 0, stream, q, k, v, X3);
  hipLaunchKernelGGL(cvt_w, dim3(16, 16, 4), dim3(256), 0, stream, Wq, Wk, Wv, Wo, WT);
  hipLaunchKernelGGL(gemm128, dim3(1536), dim3(256), 0, stream, X3, WT, bq, bk, bv,
                     bo, Qg, Kg, Vtg, out, 0, 1536);
  hipLaunchKernelGGL(attn, dim3(512), dim3(256), 0, stream, Qg, Kg, Vtg, Ctx);
  hipLaunchKernelGGL(gemm128, dim3(512), dim3(256), 0, stream, Ctx, WT, bq, bk, bv,
                     bo, Qg, Kg, Vtg, out, 3, 512);
}